// Round 6
// baseline (964.996 us; speedup 1.0000x reference)
//
#include <hip/hip_runtime.h>
#include <stdint.h>

#define BQ    256      // queries
#define NG    196608   // gallery rows
#define D3    1536     // dim
#define KK    32       // final top-k
#define KBP   16       // per-block top-k
#define WB    512      // gallery blocks
#define RPB   384      // rows per block
#define NR    128      // rows per N-step
#define NSTEPS 3       // RPB/NR
#define BK    64       // k-dim staging step
#define NKS   24       // D3/BK
#define MW    (NG/32)  // 6144 mask words per query
#define NCAND (WB*KBP) // 8192 candidates per query
#define C64   64       // rescore candidate count

typedef short  s16x8 __attribute__((ext_vector_type(8)));
typedef float  f32x4 __attribute__((ext_vector_type(4)));

#define NEG_INF (-__builtin_inff())

// lgkm-drain + raw barrier: does NOT drain vmcnt, so prefetch loads stay in flight.
#define BAR() do { __asm__ volatile("s_waitcnt lgkmcnt(0)" ::: "memory"); \
                   __builtin_amdgcn_s_barrier(); } while (0)

// ---------- fp32 -> bf16 (RNE) ----------
__device__ __forceinline__ unsigned f2bf1(float x) {
    unsigned u = __builtin_bit_cast(unsigned, x);
    return (u + 0x7fffu + ((u >> 16) & 1u)) >> 16;
}
__device__ __forceinline__ unsigned pack2(float lo, float hi) {
    return (f2bf1(hi) << 16) | f2bf1(lo);
}

// ---------- sorted-descending top-K inserts (static indexing) ----------
__device__ __forceinline__ void topkb_insert(float (&bs)[KBP], int (&bi)[KBP],
                                             float s, int idx) {
    float cs = s; int ci = idx;
#pragma unroll
    for (int m = 0; m < KBP; ++m) {
        const bool sw = cs > bs[m];
        const float ts = sw ? bs[m] : cs;
        const int   ti = sw ? bi[m] : ci;
        bs[m] = sw ? cs : bs[m];
        bi[m] = sw ? ci : bi[m];
        cs = ts; ci = ti;
    }
}
__device__ __forceinline__ void top8_insert(float (&bs)[8], int (&bi)[8],
                                            float s, int idx) {
    float cs = s; int ci = idx;
#pragma unroll
    for (int m = 0; m < 8; ++m) {
        const bool sw = cs > bs[m];
        const float ts = sw ? bs[m] : cs;
        const int   ti = sw ? bi[m] : ci;
        bs[m] = sw ? cs : bs[m];
        bi[m] = sw ? ci : bi[m];
        cs = ts; ci = ti;
    }
}

// ---------- Kernel 0a: Q fp32 -> bf16 ----------
__global__ __launch_bounds__(256)
void cvt_q(const float* __restrict__ Q, unsigned short* __restrict__ Qbf) {
    const int i = (blockIdx.x * 256 + threadIdx.x) * 8;
    const float4 a = *(const float4*)(Q + i);
    const float4 b = *(const float4*)(Q + i + 4);
    uint4 v;
    v.x = pack2(a.x, a.y); v.y = pack2(a.z, a.w);
    v.z = pack2(b.x, b.y); v.w = pack2(b.z, b.w);
    *(uint4*)(Qbf + i) = v;
}

// ---------- Kernel 0b: bitpack exclude mask (int32 -> 1 bit) ----------
__global__ __launch_bounds__(256)
void pack_mask(const int* __restrict__ M, unsigned* __restrict__ Mb) {
    const int id = blockIdx.x * 256 + threadIdx.x; // word index, q-major
    const int* src = M + (size_t)id * 32;
    unsigned wbits = 0;
#pragma unroll
    for (int c = 0; c < 8; ++c) {
        const int4 m = *(const int4*)(src + c * 4);
        wbits |= (m.x ? 1u : 0u) << (c * 4 + 0);
        wbits |= (m.y ? 1u : 0u) << (c * 4 + 1);
        wbits |= (m.z ? 1u : 0u) << (c * 4 + 2);
        wbits |= (m.w ? 1u : 0u) << (c * 4 + 3);
    }
    Mb[id] = wbits;
}

// ---------- Kernel A: pipelined bf16 MFMA scoring + per-block top-16 ----------
// LDS: G double-buffer bf16[2][128 r][64 k] (2x16KB, XOR-swizzled rows).
// Epilogue overlays per-wave slabs Sl[64 q][33] f32 @ w*8448 (33792 B total).
__global__ __launch_bounds__(256, 2)
void score_mfma(const unsigned short* __restrict__ Qbf, const float* __restrict__ G,
                const unsigned* __restrict__ Mb,
                float* __restrict__ cand_s, int* __restrict__ cand_i) {
    __shared__ __align__(16) char lds[33792];
    const int blk = blockIdx.x, t = threadIdx.x;
    const int w = t >> 6, l = t & 63;
    const int l15 = l & 15, l4 = l >> 4;
    const int r_st = t >> 1, h_st = t & 1;          // staging: 2 threads / G row
    const int rx_st = (r_st & 7) << 4;

    float bs[KBP]; int bi[KBP];
#pragma unroll
    for (int m = 0; m < KBP; ++m) { bs[m] = NEG_INF; bi[m] = -1; }

    for (int ns = 0; ns < NSTEPS; ++ns) {
        const int grow0 = blk * RPB + ns * NR;
        const float* gbase = G + (size_t)(grow0 + r_st) * D3 + h_st * 32;

        float4 f[8];
        // ---- prologue: load tile 0 to regs
#pragma unroll
        for (int c = 0; c < 8; ++c) f[c] = *(const float4*)(gbase + c * 4);
        BAR(); // previous epilogue slab readers done before overwriting buffers
        // cvt + write buf0
        {
            const int ro = r_st * 128 + h_st * 64;
#pragma unroll
            for (int c2 = 0; c2 < 4; ++c2) {
                uint4 v;
                v.x = pack2(f[2 * c2].x, f[2 * c2].y);
                v.y = pack2(f[2 * c2].z, f[2 * c2].w);
                v.z = pack2(f[2 * c2 + 1].x, f[2 * c2 + 1].y);
                v.w = pack2(f[2 * c2 + 1].z, f[2 * c2 + 1].w);
                *(uint4*)(lds + ((ro + c2 * 16) ^ rx_st)) = v;
            }
        }

        f32x4 acc[4][8];
#pragma unroll
        for (int qt = 0; qt < 4; ++qt)
#pragma unroll
            for (int rt = 0; rt < 8; ++rt) acc[qt][rt] = (f32x4)0.0f;

        int cur = 0;
        for (int ks = 0; ks < NKS; ++ks) {
            const int k0 = ks * BK;
            // ---- prefetch next tile to regs (stays in flight across barrier)
            if (ks < NKS - 1) {
                const float* src = gbase + (k0 + BK);
#pragma unroll
                for (int c = 0; c < 8; ++c) f[c] = *(const float4*)(src + c * 4);
            }
            BAR(); // buf[cur] writes visible to all waves
            // ---- MFMA phase: A from global (L2-hot Qbf), B from LDS buf[cur]
            __builtin_amdgcn_s_setprio(1);
            const char* bufb = lds + cur * 16384;
#pragma unroll
            for (int sk = 0; sk < 2; ++sk) {
                const int koff = sk * 64 + l4 * 16; // byte offset in 128B bf16 row
                s16x8 a[4];
#pragma unroll
                for (int qt = 0; qt < 4; ++qt) {
                    const int row = w * 64 + qt * 16 + l15;
                    a[qt] = *(const s16x8*)((const char*)Qbf + (size_t)row * 3072 +
                                            k0 * 2 + koff);
                }
#pragma unroll
                for (int rt = 0; rt < 8; ++rt) {
                    const int row = rt * 16 + l15;
                    const s16x8 b = *(const s16x8*)(bufb +
                                     ((row * 128 + koff) ^ ((row & 7) << 4)));
#pragma unroll
                    for (int qt = 0; qt < 4; ++qt)
                        acc[qt][rt] = __builtin_amdgcn_mfma_f32_16x16x32_bf16(
                            a[qt], b, acc[qt][rt], 0, 0, 0);
                }
            }
            __builtin_amdgcn_s_setprio(0);
            // ---- cvt + write prefetched tile into the other buffer
            if (ks < NKS - 1) {
                char* ob = lds + (cur ^ 1) * 16384;
                const int ro = r_st * 128 + h_st * 64;
#pragma unroll
                for (int c2 = 0; c2 < 4; ++c2) {
                    uint4 v;
                    v.x = pack2(f[2 * c2].x, f[2 * c2].y);
                    v.y = pack2(f[2 * c2].z, f[2 * c2].w);
                    v.z = pack2(f[2 * c2 + 1].x, f[2 * c2 + 1].y);
                    v.w = pack2(f[2 * c2 + 1].z, f[2 * c2 + 1].w);
                    *(uint4*)(ob + ((ro + c2 * 16) ^ rx_st)) = v;
                }
                cur ^= 1;
            }
        }
        BAR(); // all MFMA reads done; overlay slabs on buffers
        // ---- epilogue: per-wave slab dump + bitmask + top-k scan
        float* Slw = (float*)(lds + w * 8448); // [64][33]
        const int q = t; // this thread owns query t
        const uint4 mw4 = *(const uint4*)(Mb + (size_t)q * MW + blk * 12 + ns * 4);
        const unsigned mv[4] = {mw4.x, mw4.y, mw4.z, mw4.w};
#pragma unroll
        for (int rs = 0; rs < 4; ++rs) {
            // dump 64q x 32r (C/D: col n = lane&15, row m = (lane>>4)*4+reg)
#pragma unroll
            for (int qt = 0; qt < 4; ++qt)
#pragma unroll
                for (int r2 = 0; r2 < 2; ++r2)
#pragma unroll
                    for (int reg = 0; reg < 4; ++reg) {
                        const int qloc = qt * 16 + l4 * 4 + reg;
                        const int nloc = r2 * 16 + l15;
                        Slw[qloc * 33 + nloc] = acc[qt][rs * 2 + r2][reg];
                    }
            __asm__ volatile("s_waitcnt lgkmcnt(0)" ::: "memory");
            const unsigned m32 = mv[rs];
            const int row0 = rs * 32;
            const float* sp = Slw + l * 33;
            for (int j = 0; j < 32; ++j) {
                const float s = sp[j];
                if (s > bs[KBP - 1] && !((m32 >> j) & 1u))
                    topkb_insert(bs, bi, s, grow0 + row0 + j);
            }
            __asm__ volatile("s_waitcnt lgkmcnt(0)" ::: "memory"); // reads done pre-next-dump
        }
    }
    // ---- emit per-(query, block) top-16
    float* os = cand_s + ((size_t)t * WB + blk) * KBP;
    int*   oi = cand_i + ((size_t)t * WB + blk) * KBP;
#pragma unroll
    for (int m = 0; m < KBP; ++m) { os[m] = bs[m]; oi[m] = bi[m]; }
}

// ---------- Kernel B: merge -> bf16-top-64 -> fp32 rescore -> final top-32 ----------
__global__ __launch_bounds__(256)
void merge_rescore(const float* __restrict__ cand_s, const int* __restrict__ cand_i,
                   const float* __restrict__ Q, const float* __restrict__ G,
                   float* __restrict__ out) {
    __shared__ float Ls[2048];
    __shared__ int   Li[2048];
    __shared__ int   sel[C64];
    __shared__ float Fs[C64];
    const int q = blockIdx.x, t = threadIdx.x, l = t & 63, w = t >> 6;
    const float* cs = cand_s + (size_t)q * NCAND;
    const int*   ci = cand_i + (size_t)q * NCAND;

    // phase 1: per-thread top-8 over 32 strided candidates
    float b8[8]; int i8[8];
#pragma unroll
    for (int m = 0; m < 8; ++m) { b8[m] = NEG_INF; i8[m] = -1; }
    for (int j = 0; j < NCAND / 256; ++j) {
        const float s = cs[t + 256 * j];
        if (s > b8[7]) top8_insert(b8, i8, s, ci[t + 256 * j]);
    }
#pragma unroll
    for (int m = 0; m < 8; ++m) { Ls[t * 8 + m] = b8[m]; Li[t * 8 + m] = i8[m]; }
    __syncthreads();

    // phase 2: 64 argmax rounds, wave 0 only (no block barriers inside)
    if (t < 64) {
        for (int r = 0; r < C64; ++r) {
            float ms = NEG_INF; int mi = 0x7fffffff, mp = -1;
            for (int jj = 0; jj < 32; ++jj) {
                const float s = Ls[l + 64 * jj];
                const int  id = Li[l + 64 * jj];
                if (s > ms || (s == ms && id < mi)) { ms = s; mi = id; mp = l + 64 * jj; }
            }
#pragma unroll
            for (int off = 32; off >= 1; off >>= 1) {
                const float s2 = __shfl_xor(ms, off);
                const int   i2 = __shfl_xor(mi, off);
                const int   p2 = __shfl_xor(mp, off);
                if (s2 > ms || (s2 == ms && i2 < mi)) { ms = s2; mi = i2; mp = p2; }
            }
            if (l == 0) { sel[r] = mi; if (mp >= 0) Ls[mp] = NEG_INF; }
            __asm__ volatile("s_waitcnt lgkmcnt(0)" ::: "memory");
        }
    }
    __syncthreads();

    // phase 3: exact fp32 rescore of 64 candidates (wave w -> candidates w, w+4, ...)
    const float* qr = Q + (size_t)q * D3;
    for (int i = w; i < C64; i += 4) {
        const int idx = sel[i];
        float a = 0.0f;
        if (idx >= 0) {
            const float* gr = G + (size_t)idx * D3;
#pragma unroll
            for (int j = 0; j < 24; ++j)
                a = __builtin_fmaf(gr[l + 64 * j], qr[l + 64 * j], a);
        }
#pragma unroll
        for (int off = 32; off >= 1; off >>= 1) a += __shfl_xor(a, off);
        if (idx < 0) a = NEG_INF;
        if (l == 0) Fs[i] = a;
    }
    __syncthreads();

    // phase 4: final top-32 over 64 rescored candidates (wave 0, register-local)
    if (t < 64) {
        float s = Fs[l]; const int id = sel[l];
        for (int r = 0; r < KK; ++r) {
            float ms = s; int mi = id;
#pragma unroll
            for (int off = 32; off >= 1; off >>= 1) {
                const float s2 = __shfl_xor(ms, off);
                const int   i2 = __shfl_xor(mi, off);
                if (s2 > ms || (s2 == ms && i2 < mi)) { ms = s2; mi = i2; }
            }
            if (l == 0) {
                out[(size_t)q * KK + r] = (float)mi;                   // best_i as float
                out[(size_t)BQ * KK + (size_t)q * KK + r] = ms;        // best_s
            }
            if (s == ms && id == mi) s = NEG_INF; // self-invalidate winner
        }
    }
}

extern "C" void kernel_launch(void* const* d_in, const int* in_sizes, int n_in,
                              void* d_out, int out_size, void* d_ws, size_t ws_size,
                              hipStream_t stream) {
    (void)in_sizes; (void)n_in; (void)out_size; (void)ws_size;
    const float* Q = (const float*)d_in[0];
    const float* G = (const float*)d_in[1];
    const int*   M = (const int*)d_in[2];
    // d_in[3] = k (fixed 32)

    unsigned short* Qbf = (unsigned short*)d_ws;                       // @0, 768 KB
    unsigned* Mbits = (unsigned*)((char*)d_ws + (1u << 20));           // @1 MB, 6.29 MB
    float* cand_s = (float*)((char*)d_ws + (8u << 20));                // @8 MB, 8 MB
    int*   cand_i = (int*)((char*)d_ws + (16u << 20));                 // @16 MB, 8 MB
    float* out = (float*)d_out;

    hipLaunchKernelGGL(cvt_q, dim3(192), dim3(256), 0, stream, Q, Qbf);
    hipLaunchKernelGGL(pack_mask, dim3(BQ * MW / 256), dim3(256), 0, stream, M, Mbits);
    hipLaunchKernelGGL(score_mfma, dim3(WB), dim3(256), 0, stream, Qbf, G, Mbits, cand_s, cand_i);
    hipLaunchKernelGGL(merge_rescore, dim3(BQ), dim3(256), 0, stream, cand_s, cand_i, Q, G, out);
}